// Round 6
// baseline (493.187 us; speedup 1.0000x reference)
//
#include <hip/hip_runtime.h>

#define CROP_H 14
#define CROP_W 14
#define NBOX   512
#define NIMG   8
#define CH     256
#define IMH    200
#define IMW    200
#define PLANE   (IMH * IMW)
#define NPOS    (CROP_H * CROP_W)          // 196
#define PER_BOX (CH * NPOS)                // 50176
#define EPT     4                          // elems per thread
#define CHUNK   (256 * EPT)                // 1024 elems per block
#define NCHUNKS (PER_BOX / CHUNK)          // 49

// ---------------------------------------------------------------------------
// Prologue: race-free counting sort of boxes by image, then interleave so
// position p processes sorted rank (p%8)*64 + p/8. Linear wgid = x + 512*y
// and 512%8==0 -> XCD = x%8 for every chunk row, so each XCD's L2 serves
// taps of <=2 images for the whole kernel (vs ~8 with random placement).
// Mechanism under test: raise local-L2 hit fraction -> lower average miss
// latency on the L1-miss-queue-bound scatter path.
// ---------------------------------------------------------------------------
__global__ __launch_bounds__(NBOX) void CropAndResize_perm_kernel(
    const int* __restrict__ box_idx, int* __restrict__ perm)
{
    __shared__ int cnt[NIMG], base[NIMG], off[NIMG];
    __shared__ int sorted[NBOX];
    const int t = threadIdx.x;                 // one thread per box
    if (t < NIMG) { cnt[t] = 0; off[t] = 0; }
    __syncthreads();

    const int img = box_idx[t];
    atomicAdd(&cnt[img], 1);
    __syncthreads();

    if (t == 0) {
        int s = 0;
        #pragma unroll
        for (int j = 0; j < NIMG; ++j) { base[j] = s; s += cnt[j]; }
    }
    __syncthreads();

    const int r = base[img] + atomicAdd(&off[img], 1);   // unique rank
    sorted[r] = t;
    __syncthreads();

    perm[t] = sorted[((t & 7) << 6) + (t >> 3)];
}

// ---------------------------------------------------------------------------
// Main kernel: round-3 scatter structure, box indirected through perm[],
// 4 elems/thread (8 independent scattered 8B tap loads in flight before
// any use), nontemporal stores keep the 103 MB output out of L2.
// ---------------------------------------------------------------------------
__global__ __launch_bounds__(256, 8) void CropAndResize_60146722013533_kernel(
    const float* __restrict__ image,
    const float* __restrict__ boxes,
    const int*   __restrict__ box_idx,
    const int*   __restrict__ perm,
    float*       __restrict__ out)
{
    const int n = perm[blockIdx.x];    // box index (image<->XCD affine)
    const int t = threadIdx.x;

    __shared__ int   sy0[CROP_H], sy1[CROP_H], sx0[CROP_W], sx1[CROP_W];
    __shared__ float sly[CROP_H], slx[CROP_W];
    __shared__ int   svy[CROP_H], svx[CROP_W];
    __shared__ int   sb;

    if (t < CROP_H + CROP_W) {
        const float by1 = boxes[n * 4 + 0];
        const float bx1 = boxes[n * 4 + 1];
        const float by2 = boxes[n * 4 + 2];
        const float bx2 = boxes[n * 4 + 3];
        if (t < CROP_H) {
            const int gy = t;
            float h_scale = (by2 - by1) * (float)(IMH - 1) / (float)(CROP_H - 1);
            float in_y = by1 * (float)(IMH - 1) + (float)gy * h_scale;
            svy[gy] = (in_y >= 0.0f && in_y <= (float)(IMH - 1)) ? 1 : 0;
            float yf = floorf(in_y);
            sly[gy] = in_y - yf;
            sy0[gy] = (int)fminf(fmaxf(yf, 0.0f), (float)(IMH - 1));
            sy1[gy] = (int)fminf(fmaxf(ceilf(in_y), 0.0f), (float)(IMH - 1));
        } else {
            const int gx = t - CROP_H;
            float w_scale = (bx2 - bx1) * (float)(IMW - 1) / (float)(CROP_W - 1);
            float in_x = bx1 * (float)(IMW - 1) + (float)gx * w_scale;
            svx[gx] = (in_x >= 0.0f && in_x <= (float)(IMW - 1)) ? 1 : 0;
            float xf = floorf(in_x);
            slx[gx] = in_x - xf;
            sx0[gx] = (int)fminf(fmaxf(xf, 0.0f), (float)(IMW - 1));
            sx1[gx] = (int)fminf(fmaxf(ceilf(in_x), 0.0f), (float)(IMW - 1));
        }
    }
    if (t == 0) sb = box_idx[n];
    __syncthreads();

    const int base = blockIdx.y * CHUNK;
    const float* __restrict__ img = image + (size_t)sb * CH * PLANE;
    float* __restrict__ ob = out + (size_t)n * PER_BOX + base + t;

    // per-elem state (fully unrolled -> registers, rule #20 safe)
    const float* rt[EPT];
    const float* rb[EPT];
    int   xa[EPT], xbn[EPT], x1v[EPT], vm[EPT];
    float lyv[EPT], lxv[EPT];

    #pragma unroll
    for (int k = 0; k < EPT; ++k) {
        const int elem = base + t + 256 * k;
        const int c  = elem / NPOS;
        const int r  = elem - c * NPOS;
        const int gy = r / CROP_W;
        const int gx = r - gy * CROP_W;
        const int x0 = sx0[gx];
        const int xb = (x0 < IMW - 2) ? x0 : (IMW - 2);
        const float* p = img + (size_t)c * PLANE;
        rt[k]  = p + sy0[gy] * IMW + xb;
        rb[k]  = p + sy1[gy] * IMW + xb;
        xa[k]  = x0;
        xbn[k] = xb;
        x1v[k] = sx1[gx];
        vm[k]  = svy[gy] & svx[gx];
        lyv[k] = sly[gy];
        lxv[k] = slx[gx];
    }

    // issue all 8 scattered 8B loads before any use
    float2 vt[EPT], vb[EPT];
    #pragma unroll
    for (int k = 0; k < EPT; ++k) {
        __builtin_memcpy(&vt[k], rt[k], 8);
        __builtin_memcpy(&vb[k], rb[k], 8);
    }

    #pragma unroll
    for (int k = 0; k < EPT; ++k) {
        const float tl = (xa[k]  == xbn[k]) ? vt[k].x : vt[k].y;
        const float tr = (x1v[k] == xbn[k]) ? vt[k].x : vt[k].y;
        const float bl = (xa[k]  == xbn[k]) ? vb[k].x : vb[k].y;
        const float br = (x1v[k] == xbn[k]) ? vb[k].x : vb[k].y;
        const float top = tl + (tr - tl) * lxv[k];
        const float bot = bl + (br - bl) * lxv[k];
        float val = top + (bot - top) * lyv[k];
        if (!vm[k]) val = 0.0f;
        __builtin_nontemporal_store(val, ob + 256 * k);
    }
}

extern "C" void kernel_launch(void* const* d_in, const int* in_sizes, int n_in,
                              void* d_out, int out_size, void* d_ws, size_t ws_size,
                              hipStream_t stream) {
    const float* image   = (const float*)d_in[0];
    const float* boxes   = (const float*)d_in[1];
    const int*   box_idx = (const int*)d_in[2];
    float* out  = (float*)d_out;
    int*   perm = (int*)d_ws;               // 512 ints in workspace

    CropAndResize_perm_kernel<<<dim3(1, 1, 1), dim3(NBOX, 1, 1), 0, stream>>>(
        box_idx, perm);

    dim3 grid(NBOX, NCHUNKS, 1);   // x = box (fastest; XCD = x%8), y = chunk
    dim3 block(256, 1, 1);
    CropAndResize_60146722013533_kernel<<<grid, block, 0, stream>>>(
        image, boxes, box_idx, perm, out);
}